// Round 6
// baseline (243.588 us; speedup 1.0000x reference)
//
#include <hip/hip_runtime.h>
#include <stdint.h>

typedef short short4v __attribute__((ext_vector_type(4)));
typedef short short8  __attribute__((ext_vector_type(8)));
typedef float f32x4   __attribute__((ext_vector_type(4)));
typedef unsigned int u32x2 __attribute__((ext_vector_type(2)));

#define S_LEN 2048
#define NB    2
#define NH    16
#define HD    64
#define EMB   1024
#define TOK   (NB * S_LEN)     // 4096
#define QKV_N (3 * EMB)        // 3072

// async global->LDS, 16B per lane, LDS dest = wave-uniform base + lane*16
#define GLD16(gp, lp) __builtin_amdgcn_global_load_lds( \
    (const __attribute__((address_space(1))) void*)(gp), \
    (__attribute__((address_space(3))) void*)(lp), 16, 0, 0)

static __device__ __forceinline__ short f2bf(float f) {
    unsigned int x = __float_as_uint(f);
    unsigned int r = (x + 0x7fffu + ((x >> 16) & 1u)) >> 16;   // RNE
    return (short)(r & 0xffffu);
}

static __device__ __forceinline__ f32x4 mfma16(short8 a, short8 b, f32x4 c) {
    return __builtin_amdgcn_mfma_f32_16x16x32_bf16(a, b, c, 0, 0, 0);
}

// ---------------------------------------------------------------- prep ----
__global__ __launch_bounds__(256) void cvt_f32_bf16(const float* __restrict__ in,
                                                    short* __restrict__ out, int n) {
    int i = (blockIdx.x * 256 + threadIdx.x) * 4;
    if (i < n) {
        float4 v = *reinterpret_cast<const float4*>(in + i);
        short4v o;
        o.x = f2bf(v.x); o.y = f2bf(v.y); o.z = f2bf(v.z); o.w = f2bf(v.w);
        *reinterpret_cast<short4v*>(out + i) = o;
    }
}

// W[K][N] fp32 -> WT[N][K] bf16
__global__ __launch_bounds__(256) void transpose_cvt(const float* __restrict__ w,
                                                     short* __restrict__ wt,
                                                     int K, int N) {
    __shared__ float tile[32][33];
    int tx = threadIdx.x & 31, ty = threadIdx.x >> 5;   // 32 x 8
    int c0 = blockIdx.x * 32, r0 = blockIdx.y * 32;
    #pragma unroll
    for (int j = 0; j < 4; j++)
        tile[ty + j * 8][tx] = w[(long)(r0 + ty + j * 8) * N + c0 + tx];
    __syncthreads();
    #pragma unroll
    for (int j = 0; j < 4; j++)
        wt[(long)(c0 + ty + j * 8) * K + r0 + tx] = f2bf(tile[tx][ty + j * 8]);
}

// V [bh][s][d] bf16 -> Vt [bh][d][s] bf16
__global__ __launch_bounds__(256) void vtrans(const short* __restrict__ v,
                                              short* __restrict__ vt) {
    __shared__ short t[32][33];
    int tx = threadIdx.x & 31, ty = threadIdx.x >> 5;
    int s0 = blockIdx.x * 32, d0 = blockIdx.y * 32, bh = blockIdx.z;
    const long base = (long)bh * S_LEN * HD;
    #pragma unroll
    for (int j = 0; j < 4; j++)
        t[ty + j * 8][tx] = v[base + (long)(s0 + ty + j * 8) * HD + d0 + tx];
    __syncthreads();
    #pragma unroll
    for (int j = 0; j < 4; j++)
        vt[base + (long)(d0 + ty + j * 8) * S_LEN + s0 + tx] = t[tx][ty + j * 8];
}

// ---------------------------------------------------------------- GEMM ----
// C[M][N] = A[M][K] @ BT[N][K]^T + bias.  BK=64, global_load_lds + XOR swizzle.
// EPI=0: store bf16 to q/k/v [bh][s][d].  EPI=1: fp32 row-major out.
template <int EPI>
__global__ __launch_bounds__(256) void gemm_bf16(
    const short* __restrict__ A, const short* __restrict__ BT,
    const float* __restrict__ bias,
    short* __restrict__ q_ws, short* __restrict__ k_ws, short* __restrict__ v_ws,
    float* __restrict__ outf, int M, int N, int K) {
    __shared__ __align__(16) short As[128 * 64];
    __shared__ __align__(16) short Bs[128 * 64];
    const int tid = threadIdx.x;
    const int lane = tid & 63, wave = tid >> 6;
    const int wm = wave >> 1, wn = wave & 1;
    const int l15 = lane & 15, lhi = lane >> 4;
    const int bm = blockIdx.y, bn = blockIdx.x;

    const short* gA[4]; const short* gB[4]; short* lA[4]; short* lB[4];
    #pragma unroll
    for (int i = 0; i < 4; i++) {
        int inst = wave * 4 + i;                 // 0..15
        int row  = inst * 8 + (lane >> 3);       // 0..127
        int c    = lane & 7, cp = c ^ (row & 7); // 16B-granule swizzle
        gA[i] = A  + (long)(bm * 128 + row) * K + cp * 8;
        gB[i] = BT + (long)(bn * 128 + row) * K + cp * 8;
        lA[i] = As + inst * 512;
        lB[i] = Bs + inst * 512;
    }

    f32x4 acc[4][4] = {};
    for (int kt = 0; kt < K; kt += 64) {
        #pragma unroll
        for (int i = 0; i < 4; i++) { GLD16(gA[i] + kt, lA[i]); GLD16(gB[i] + kt, lB[i]); }
        __syncthreads();
        #pragma unroll
        for (int ks = 0; ks < 2; ks++) {
            short8 af[4], bfr[4];
            #pragma unroll
            for (int m = 0; m < 4; m++) {
                int row = wm * 64 + m * 16 + l15;
                int cp  = (ks * 4 + lhi) ^ (row & 7);
                af[m] = *(const short8*)(As + row * 64 + cp * 8);
            }
            #pragma unroll
            for (int n = 0; n < 4; n++) {
                int row = wn * 64 + n * 16 + l15;
                int cp  = (ks * 4 + lhi) ^ (row & 7);
                bfr[n] = *(const short8*)(Bs + row * 64 + cp * 8);
            }
            #pragma unroll
            for (int m = 0; m < 4; m++)
                #pragma unroll
                for (int n = 0; n < 4; n++)
                    acc[m][n] = mfma16(af[m], bfr[n], acc[m][n]);
        }
        __syncthreads();
    }

    if (EPI == 0) {
        const int part = bn >> 3;                // 1024-aligned: uniform per block
        short* dst = part == 0 ? q_ws : (part == 1 ? k_ws : v_ws);
        #pragma unroll
        for (int m = 0; m < 4; m++) {
            const int row0 = bm * 128 + wm * 64 + m * 16 + lhi * 4;
            #pragma unroll
            for (int n = 0; n < 4; n++) {
                const int col = bn * 128 + wn * 64 + n * 16 + l15;
                const float bv = bias[col];
                const int nn = col & 1023, h = nn >> 6, d = nn & 63;
                #pragma unroll
                for (int r = 0; r < 4; r++) {
                    const int rr = row0 + r, b = rr >> 11, s = rr & 2047;
                    dst[((long)(b * NH + h) * S_LEN + s) * HD + d] =
                        f2bf(acc[m][n][r] + bv);
                }
            }
        }
    } else {
        #pragma unroll
        for (int m = 0; m < 4; m++) {
            const int row0 = bm * 128 + wm * 64 + m * 16 + lhi * 4;
            #pragma unroll
            for (int n = 0; n < 4; n++) {
                const int col = bn * 128 + wn * 64 + n * 16 + l15;
                const float bv = bias[col];
                #pragma unroll
                for (int r = 0; r < 4; r++)
                    outf[(long)(row0 + r) * N + col] = acc[m][n][r] + bv;
            }
        }
    }
}

// ----------------------------------------------------------- attention ----
// Q,K: [bh][s][d].  Vt: [bh][d][s].  O: [b][s][e] bf16.
// 4 waves x 16 q-rows; KVBLK=64; double-buffered K/V (1 barrier/tile);
// round-2-proven softmax numerics (max tree + defer-max + f32 lrow).
__global__ __launch_bounds__(256) void attn_fwd(const short* __restrict__ Qg,
                                                const short* __restrict__ Kg,
                                                const short* __restrict__ Vtg,
                                                short* __restrict__ Og) {
    __shared__ __align__(16) short Ks[2][4096];
    __shared__ __align__(16) short Vs[2][4096];
    __shared__ __align__(16) short Pl[4][16][72];
    const int tid = threadIdx.x, lane = tid & 63, wave = tid >> 6;
    const int l15 = lane & 15, lhi = lane >> 4;
    // bijective XCD swizzle: 1024 wgs, 8 XCDs -> 4 heads per XCD's L2
    const int wg  = blockIdx.x;
    const int swz = (wg & 7) * 128 + (wg >> 3);
    const int bh  = swz >> 5;
    const int qt  = swz & 31;
    const int q0 = qt * 64 + wave * 16;
    const long kbase = (long)bh * S_LEN * HD;
    const long vbase = (long)bh * HD * S_LEN;

    short8 qf[2];
    #pragma unroll
    for (int ks2 = 0; ks2 < 2; ks2++)
        qf[ks2] = *(const short8*)&Qg[kbase + (long)(q0 + l15) * HD + ks2 * 32 + lhi * 8];

    const short* gKp[2]; const short* gVp[2]; int lOff[2];
    #pragma unroll
    for (int i = 0; i < 2; i++) {
        int inst = wave * 2 + i;                 // 0..7
        int row  = inst * 8 + (lane >> 3);       // 0..63
        int cp   = (lane & 7) ^ (row & 7);
        gKp[i] = Kg  + kbase + (long)row * HD + cp * 8;
        gVp[i] = Vtg + vbase + (long)row * S_LEN + cp * 8;
        lOff[i] = inst * 512;
    }

    // loop-invariant swizzled fragment offsets (element units)
    int fOff[4][2];
    #pragma unroll
    for (int sub = 0; sub < 4; sub++)
        #pragma unroll
        for (int ks2 = 0; ks2 < 2; ks2++) {
            int row = sub * 16 + l15;
            int cp  = (ks2 * 4 + lhi) ^ (l15 & 7);
            fOff[sub][ks2] = row * 64 + cp * 8;
        }

    f32x4 accO[4] = {};
    float ms = -1e30f, lp = 0.f;
    const float C2 = 0.18033688f;   // (1/sqrt(64)) * log2(e)

    #pragma unroll
    for (int i = 0; i < 2; i++) { GLD16(gKp[i], &Ks[0][lOff[i]]); GLD16(gVp[i], &Vs[0][lOff[i]]); }
    __syncthreads();

    const int NT = S_LEN / 64;
    for (int t = 0; t < NT; t++) {
        const int cur = t & 1;
        if (t + 1 < NT) {       // stage next tile into other half (overlaps compute)
            #pragma unroll
            for (int i = 0; i < 2; i++) {
                GLD16(gKp[i] + (long)(t + 1) * 4096, &Ks[cur ^ 1][lOff[i]]);
                GLD16(gVp[i] + (t + 1) * 64,         &Vs[cur ^ 1][lOff[i]]);
            }
        }
        // S = Q K^T -> lane holds S[q=l15][k=sub*16+lhi*4+r]
        f32x4 accS[4];
        #pragma unroll
        for (int sub = 0; sub < 4; sub++) {
            f32x4 z = {0.f, 0.f, 0.f, 0.f};
            #pragma unroll
            for (int ks2 = 0; ks2 < 2; ks2++) {
                short8 kf = *(const short8*)&Ks[cur][fOff[sub][ks2]];
                z = mfma16(kf, qf[ks2], z);
            }
            accS[sub] = z;
        }

        // row max: in-register tree + 2 cross-lhi shuffles
        f32x4 mx = accS[0];
        #pragma unroll
        for (int sub = 1; sub < 4; sub++)
            #pragma unroll
            for (int r = 0; r < 4; r++) mx[r] = fmaxf(mx[r], accS[sub][r]);
        float m4 = fmaxf(fmaxf(mx[0], mx[1]), fmaxf(mx[2], mx[3]));
        m4 = fmaxf(m4, __shfl_xor(m4, 16));
        m4 = fmaxf(m4, __shfl_xor(m4, 32));
        float msc = m4 * C2;

        // defer-max (T13): rescale only when max grew by > 8 (exp2 domain)
        if (__any(msc > ms + 8.f)) {
            float msn = fmaxf(ms, msc);
            float corr = exp2f(ms - msn);
            ms = msn;
            lp *= corr;
            #pragma unroll
            for (int r = 0; r < 4; r++) {
                float cr = __shfl(corr, lhi * 4 + r);   // corr of q-row (lhi*4+r)
                #pragma unroll
                for (int ds = 0; ds < 4; ds++) accO[ds][r] *= cr;
            }
        }

        // P = exp2(S*C2 - ms); per-lane f32 partial sum; pack bf16, b64 write
        float lsum = 0.f;
        #pragma unroll
        for (int sub = 0; sub < 4; sub++) {
            f32x4 p;
            #pragma unroll
            for (int r = 0; r < 4; r++)
                p[r] = exp2f(fmaf(accS[sub][r], C2, -ms));
            lsum += (p[0] + p[1]) + (p[2] + p[3]);
            unsigned pa, pb;
            asm("v_cvt_pk_bf16_f32 %0, %1, %2" : "=v"(pa) : "v"(p[0]), "v"(p[1]));
            asm("v_cvt_pk_bf16_f32 %0, %1, %2" : "=v"(pb) : "v"(p[2]), "v"(p[3]));
            u32x2 w; w[0] = pa; w[1] = pb;
            *(u32x2*)(&Pl[wave][l15][sub * 16 + lhi * 4]) = w;
        }
        lp += lsum;

        asm volatile("s_waitcnt lgkmcnt(0)" ::: "memory");
        __builtin_amdgcn_sched_barrier(0);
        short8 pf0 = *(const short8*)(&Pl[wave][l15][lhi * 8]);
        short8 pf1 = *(const short8*)(&Pl[wave][l15][32 + lhi * 8]);
        // O += P V
        #pragma unroll
        for (int ds = 0; ds < 4; ds++) {
            short8 vf0 = *(const short8*)&Vs[cur][fOff[ds][0]];
            short8 vf1 = *(const short8*)&Vs[cur][fOff[ds][1]];
            accO[ds] = mfma16(pf0, vf0, accO[ds]);
            accO[ds] = mfma16(pf1, vf1, accO[ds]);
        }
        __syncthreads();
    }

    // final: reduce row sums across lhi, redistribute to accO layout, store
    float L = lp + __shfl_xor(lp, 16);
    L += __shfl_xor(L, 32);
    const int b = bh >> 4, h = bh & 15;
    #pragma unroll
    for (int r = 0; r < 4; r++) {
        float Lr  = __shfl(L, lhi * 4 + r);
        float inv = 1.f / Lr;
        const int s = q0 + lhi * 4 + r;
        #pragma unroll
        for (int ds = 0; ds < 4; ds++)
            Og[((long)(b * S_LEN + s)) * EMB + h * 64 + ds * 16 + l15] =
                f2bf(accO[ds][r] * inv);
    }
}

// -------------------------------------------------------------- launch ----
extern "C" void kernel_launch(void* const* d_in, const int* in_sizes, int n_in,
                              void* d_out, int out_size, void* d_ws, size_t ws_size,
                              hipStream_t stream) {
    const float* x    = (const float*)d_in[0];
    const float* qkvw = (const float*)d_in[1];
    const float* qkvb = (const float*)d_in[2];
    const float* outw = (const float*)d_in[3];
    const float* outb = (const float*)d_in[4];
    float* out = (float*)d_out;

    char* ws = (char*)d_ws;
    size_t off = 0;
    auto alloc = [&](size_t bytes) {
        void* p = ws + off;
        off += (bytes + 255) & ~(size_t)255;
        return p;
    };
    short* xb    = (short*)alloc((size_t)TOK * EMB * 2);
    short* wqkvT = (short*)alloc((size_t)QKV_N * EMB * 2);
    short* owT   = (short*)alloc((size_t)EMB * EMB * 2);
    short* q_ws  = (short*)alloc((size_t)NB * NH * S_LEN * HD * 2);
    short* k_ws  = (short*)alloc((size_t)NB * NH * S_LEN * HD * 2);
    short* v_ws  = (short*)alloc((size_t)NB * NH * S_LEN * HD * 2);
    short* vt_ws = (short*)alloc((size_t)NB * NH * S_LEN * HD * 2);
    short* attn  = (short*)alloc((size_t)TOK * EMB * 2);

    cvt_f32_bf16<<<(TOK * EMB / 4 + 255) / 256, 256, 0, stream>>>(x, xb, TOK * EMB);
    transpose_cvt<<<dim3(QKV_N / 32, EMB / 32), 256, 0, stream>>>(qkvw, wqkvT, EMB, QKV_N);
    transpose_cvt<<<dim3(EMB / 32, EMB / 32), 256, 0, stream>>>(outw, owT, EMB, EMB);

    gemm_bf16<0><<<dim3(QKV_N / 128, TOK / 128), 256, 0, stream>>>(
        xb, wqkvT, qkvb, q_ws, k_ws, v_ws, nullptr, TOK, QKV_N, EMB);

    vtrans<<<dim3(S_LEN / 32, HD / 32, NB * NH), 256, 0, stream>>>(v_ws, vt_ws);

    attn_fwd<<<1024, 256, 0, stream>>>(q_ws, k_ws, vt_ws, attn);

    gemm_bf16<1><<<dim3(EMB / 128, TOK / 128), 256, 0, stream>>>(
        attn, owT, outb, nullptr, nullptr, nullptr, out, TOK, EMB, EMB);
}

// Round 7
// 230.148 us; speedup vs baseline: 1.0584x; 1.0584x over previous
//
#include <hip/hip_runtime.h>
#include <stdint.h>

typedef short short4v __attribute__((ext_vector_type(4)));
typedef short short8  __attribute__((ext_vector_type(8)));
typedef float f32x4   __attribute__((ext_vector_type(4)));
typedef unsigned int u32x2 __attribute__((ext_vector_type(2)));

#define S_LEN 2048
#define NB    2
#define NH    16
#define HD    64
#define EMB   1024
#define TOK   (NB * S_LEN)     // 4096
#define QKV_N (3 * EMB)        // 3072

// async global->LDS, 16B per lane, LDS dest = wave-uniform base + lane*16
#define GLD16(gp, lp) __builtin_amdgcn_global_load_lds( \
    (const __attribute__((address_space(1))) void*)(gp), \
    (__attribute__((address_space(3))) void*)(lp), 16, 0, 0)

static __device__ __forceinline__ short f2bf(float f) {
    unsigned int x = __float_as_uint(f);
    unsigned int r = (x + 0x7fffu + ((x >> 16) & 1u)) >> 16;   // RNE
    return (short)(r & 0xffffu);
}

static __device__ __forceinline__ f32x4 mfma16(short8 a, short8 b, f32x4 c) {
    return __builtin_amdgcn_mfma_f32_16x16x32_bf16(a, b, c, 0, 0, 0);
}

// ---------------------------------------------------------------- prep ----
__global__ __launch_bounds__(256) void cvt_f32_bf16(const float* __restrict__ in,
                                                    short* __restrict__ out, int n) {
    int i = (blockIdx.x * 256 + threadIdx.x) * 4;
    if (i < n) {
        float4 v = *reinterpret_cast<const float4*>(in + i);
        short4v o;
        o.x = f2bf(v.x); o.y = f2bf(v.y); o.z = f2bf(v.z); o.w = f2bf(v.w);
        *reinterpret_cast<short4v*>(out + i) = o;
    }
}

// W[K][N] fp32 -> WT[N][K] bf16
__global__ __launch_bounds__(256) void transpose_cvt(const float* __restrict__ w,
                                                     short* __restrict__ wt,
                                                     int K, int N) {
    __shared__ float tile[32][33];
    int tx = threadIdx.x & 31, ty = threadIdx.x >> 5;   // 32 x 8
    int c0 = blockIdx.x * 32, r0 = blockIdx.y * 32;
    #pragma unroll
    for (int j = 0; j < 4; j++)
        tile[ty + j * 8][tx] = w[(long)(r0 + ty + j * 8) * N + c0 + tx];
    __syncthreads();
    #pragma unroll
    for (int j = 0; j < 4; j++)
        wt[(long)(c0 + ty + j * 8) * K + r0 + tx] = f2bf(tile[tx][ty + j * 8]);
}

// V [bh][s][d] bf16 -> Vt [bh][d][s] bf16
__global__ __launch_bounds__(256) void vtrans(const short* __restrict__ v,
                                              short* __restrict__ vt) {
    __shared__ short t[32][33];
    int tx = threadIdx.x & 31, ty = threadIdx.x >> 5;
    int s0 = blockIdx.x * 32, d0 = blockIdx.y * 32, bh = blockIdx.z;
    const long base = (long)bh * S_LEN * HD;
    #pragma unroll
    for (int j = 0; j < 4; j++)
        t[ty + j * 8][tx] = v[base + (long)(s0 + ty + j * 8) * HD + d0 + tx];
    __syncthreads();
    #pragma unroll
    for (int j = 0; j < 4; j++)
        vt[base + (long)(d0 + ty + j * 8) * S_LEN + s0 + tx] = t[tx][ty + j * 8];
}

// ---------------------------------------------------------------- GEMM ----
// C[M][N] = A[M][K] @ BT[N][K]^T + bias.  BK=64, global_load_lds + XOR swizzle.
// EPI=0: store bf16 to q/k/v [bh][s][d].  EPI=1: fp32 row-major out.
template <int EPI>
__global__ __launch_bounds__(256) void gemm_bf16(
    const short* __restrict__ A, const short* __restrict__ BT,
    const float* __restrict__ bias,
    short* __restrict__ q_ws, short* __restrict__ k_ws, short* __restrict__ v_ws,
    float* __restrict__ outf, int M, int N, int K) {
    __shared__ __align__(16) short As[128 * 64];
    __shared__ __align__(16) short Bs[128 * 64];
    const int tid = threadIdx.x;
    const int lane = tid & 63, wave = tid >> 6;
    const int wm = wave >> 1, wn = wave & 1;
    const int l15 = lane & 15, lhi = lane >> 4;
    const int bm = blockIdx.y, bn = blockIdx.x;

    const short* gA[4]; const short* gB[4]; short* lA[4]; short* lB[4];
    #pragma unroll
    for (int i = 0; i < 4; i++) {
        int inst = wave * 4 + i;                 // 0..15
        int row  = inst * 8 + (lane >> 3);       // 0..127
        int c    = lane & 7, cp = c ^ (row & 7); // 16B-granule swizzle
        gA[i] = A  + (long)(bm * 128 + row) * K + cp * 8;
        gB[i] = BT + (long)(bn * 128 + row) * K + cp * 8;
        lA[i] = As + inst * 512;
        lB[i] = Bs + inst * 512;
    }

    f32x4 acc[4][4] = {};
    for (int kt = 0; kt < K; kt += 64) {
        #pragma unroll
        for (int i = 0; i < 4; i++) { GLD16(gA[i] + kt, lA[i]); GLD16(gB[i] + kt, lB[i]); }
        __syncthreads();
        #pragma unroll
        for (int ks = 0; ks < 2; ks++) {
            short8 af[4], bfr[4];
            #pragma unroll
            for (int m = 0; m < 4; m++) {
                int row = wm * 64 + m * 16 + l15;
                int cp  = (ks * 4 + lhi) ^ (row & 7);
                af[m] = *(const short8*)(As + row * 64 + cp * 8);
            }
            #pragma unroll
            for (int n = 0; n < 4; n++) {
                int row = wn * 64 + n * 16 + l15;
                int cp  = (ks * 4 + lhi) ^ (row & 7);
                bfr[n] = *(const short8*)(Bs + row * 64 + cp * 8);
            }
            #pragma unroll
            for (int m = 0; m < 4; m++)
                #pragma unroll
                for (int n = 0; n < 4; n++)
                    acc[m][n] = mfma16(af[m], bfr[n], acc[m][n]);
        }
        __syncthreads();
    }

    if (EPI == 0) {
        const int part = bn >> 3;                // 1024-aligned: uniform per block
        short* dst = part == 0 ? q_ws : (part == 1 ? k_ws : v_ws);
        #pragma unroll
        for (int m = 0; m < 4; m++) {
            const int row0 = bm * 128 + wm * 64 + m * 16 + lhi * 4;
            #pragma unroll
            for (int n = 0; n < 4; n++) {
                const int col = bn * 128 + wn * 64 + n * 16 + l15;
                const float bv = bias[col];
                const int nn = col & 1023, h = nn >> 6, d = nn & 63;
                #pragma unroll
                for (int r = 0; r < 4; r++) {
                    const int rr = row0 + r, b = rr >> 11, s = rr & 2047;
                    dst[((long)(b * NH + h) * S_LEN + s) * HD + d] =
                        f2bf(acc[m][n][r] + bv);
                }
            }
        }
    } else {
        #pragma unroll
        for (int m = 0; m < 4; m++) {
            const int row0 = bm * 128 + wm * 64 + m * 16 + lhi * 4;
            #pragma unroll
            for (int n = 0; n < 4; n++) {
                const int col = bn * 128 + wn * 64 + n * 16 + l15;
                const float bv = bias[col];
                #pragma unroll
                for (int r = 0; r < 4; r++)
                    outf[(long)(row0 + r) * N + col] = acc[m][n][r] + bv;
            }
        }
    }
}

// ----------------------------------------------------------- attention ----
// Q,K: [bh][s][d].  Vt: [bh][d][s].  O: [b][s][e] bf16.
// 4 waves x 16 q-rows; KVBLK=64.  K double-buffered, V single-buffered
// (V consumed last, staged at tile top -> overlaps QK+softmax).  2 barriers/
// tile.  LDS 33792 B -> 4 blocks/CU.  Round-2-proven softmax numerics.
__global__ __launch_bounds__(256) void attn_fwd(const short* __restrict__ Qg,
                                                const short* __restrict__ Kg,
                                                const short* __restrict__ Vtg,
                                                short* __restrict__ Og) {
    __shared__ __align__(16) short Ks[2][4096];
    __shared__ __align__(16) short Vs[4096];
    __shared__ __align__(16) short Pl[4][16][72];
    const int tid = threadIdx.x, lane = tid & 63, wave = tid >> 6;
    const int l15 = lane & 15, lhi = lane >> 4;
    // bijective XCD swizzle: 1024 wgs, 8 XCDs -> 4 heads per XCD's L2
    const int wg  = blockIdx.x;
    const int swz = (wg & 7) * 128 + (wg >> 3);
    const int bh  = swz >> 5;
    const int qt  = swz & 31;
    const int q0 = qt * 64 + wave * 16;
    const long kbase = (long)bh * S_LEN * HD;
    const long vbase = (long)bh * HD * S_LEN;

    short8 qf[2];
    #pragma unroll
    for (int ks2 = 0; ks2 < 2; ks2++)
        qf[ks2] = *(const short8*)&Qg[kbase + (long)(q0 + l15) * HD + ks2 * 32 + lhi * 8];

    const short* gKp[2]; const short* gVp[2]; int lOff[2];
    #pragma unroll
    for (int i = 0; i < 2; i++) {
        int inst = wave * 2 + i;                 // 0..7
        int row  = inst * 8 + (lane >> 3);       // 0..63
        int cp   = (lane & 7) ^ (row & 7);
        gKp[i] = Kg  + kbase + (long)row * HD + cp * 8;
        gVp[i] = Vtg + vbase + (long)row * S_LEN + cp * 8;
        lOff[i] = inst * 512;
    }

    // loop-invariant swizzled fragment offsets (element units)
    int fOff[4][2];
    #pragma unroll
    for (int sub = 0; sub < 4; sub++)
        #pragma unroll
        for (int ks2 = 0; ks2 < 2; ks2++) {
            int row = sub * 16 + l15;
            int cp  = (ks2 * 4 + lhi) ^ (l15 & 7);
            fOff[sub][ks2] = row * 64 + cp * 8;
        }

    f32x4 accO[4] = {};
    float ms = -1e30f, lp = 0.f;
    const float C2 = 0.18033688f;   // (1/sqrt(64)) * log2(e)

    // prologue: stage K(0) only; V(0) staged at t=0 tile top
    #pragma unroll
    for (int i = 0; i < 2; i++) GLD16(gKp[i], &Ks[0][lOff[i]]);
    __syncthreads();

    const int NT = S_LEN / 64;
    for (int t = 0; t < NT; t++) {
        const int cur = t & 1;
        // stage V(t) into single buffer (safe: barrier-B of t-1 passed);
        // consumed after barrier-A below.
        #pragma unroll
        for (int i = 0; i < 2; i++) GLD16(gVp[i] + t * 64, &Vs[lOff[i]]);
        // stage K(t+1) into the other K half
        if (t + 1 < NT) {
            #pragma unroll
            for (int i = 0; i < 2; i++)
                GLD16(gKp[i] + (long)(t + 1) * 4096, &Ks[cur ^ 1][lOff[i]]);
        }

        // S = Q K^T -> lane holds S[q=l15][k=sub*16+lhi*4+r]
        f32x4 accS[4];
        #pragma unroll
        for (int sub = 0; sub < 4; sub++) {
            f32x4 z = {0.f, 0.f, 0.f, 0.f};
            #pragma unroll
            for (int ks2 = 0; ks2 < 2; ks2++) {
                short8 kf = *(const short8*)&Ks[cur][fOff[sub][ks2]];
                z = mfma16(kf, qf[ks2], z);
            }
            accS[sub] = z;
        }

        // row max: in-register tree + 2 cross-lhi shuffles
        f32x4 mx = accS[0];
        #pragma unroll
        for (int sub = 1; sub < 4; sub++)
            #pragma unroll
            for (int r = 0; r < 4; r++) mx[r] = fmaxf(mx[r], accS[sub][r]);
        float m4 = fmaxf(fmaxf(mx[0], mx[1]), fmaxf(mx[2], mx[3]));
        m4 = fmaxf(m4, __shfl_xor(m4, 16));
        m4 = fmaxf(m4, __shfl_xor(m4, 32));
        float msc = m4 * C2;

        // defer-max (T13): rescale only when max grew by > 8 (exp2 domain)
        if (__any(msc > ms + 8.f)) {
            float msn = fmaxf(ms, msc);
            float corr = exp2f(ms - msn);
            ms = msn;
            lp *= corr;
            #pragma unroll
            for (int r = 0; r < 4; r++) {
                float cr = __shfl(corr, lhi * 4 + r);   // corr of q-row (lhi*4+r)
                #pragma unroll
                for (int ds = 0; ds < 4; ds++) accO[ds][r] *= cr;
            }
        }

        // P = exp2(S*C2 - ms); per-lane f32 partial sum; pack bf16, b64 write
        float lsum = 0.f;
        #pragma unroll
        for (int sub = 0; sub < 4; sub++) {
            f32x4 p;
            #pragma unroll
            for (int r = 0; r < 4; r++)
                p[r] = exp2f(fmaf(accS[sub][r], C2, -ms));
            lsum += (p[0] + p[1]) + (p[2] + p[3]);
            unsigned pa, pb;
            asm("v_cvt_pk_bf16_f32 %0, %1, %2" : "=v"(pa) : "v"(p[0]), "v"(p[1]));
            asm("v_cvt_pk_bf16_f32 %0, %1, %2" : "=v"(pb) : "v"(p[2]), "v"(p[3]));
            u32x2 w; w[0] = pa; w[1] = pb;
            *(u32x2*)(&Pl[wave][l15][sub * 16 + lhi * 4]) = w;
        }
        lp += lsum;

        // barrier-A: drains vmcnt (V(t), K(t+1) landed) and lgkm (Pl visible)
        __syncthreads();

        short8 pf0 = *(const short8*)(&Pl[wave][l15][lhi * 8]);
        short8 pf1 = *(const short8*)(&Pl[wave][l15][32 + lhi * 8]);
        // O += P V
        #pragma unroll
        for (int ds = 0; ds < 4; ds++) {
            short8 vf0 = *(const short8*)&Vs[fOff[ds][0]];
            short8 vf1 = *(const short8*)&Vs[fOff[ds][1]];
            accO[ds] = mfma16(pf0, vf0, accO[ds]);
            accO[ds] = mfma16(pf1, vf1, accO[ds]);
        }
        // barrier-B: protect Vs (and Pl) before next tile overwrites
        __syncthreads();
    }

    // final: reduce row sums across lhi, redistribute to accO layout, store
    float L = lp + __shfl_xor(lp, 16);
    L += __shfl_xor(L, 32);
    const int b = bh >> 4, h = bh & 15;
    #pragma unroll
    for (int r = 0; r < 4; r++) {
        float Lr  = __shfl(L, lhi * 4 + r);
        float inv = 1.f / Lr;
        const int s = q0 + lhi * 4 + r;
        #pragma unroll
        for (int ds = 0; ds < 4; ds++)
            Og[((long)(b * S_LEN + s)) * EMB + h * 64 + ds * 16 + l15] =
                f2bf(accO[ds][r] * inv);
    }
}

// -------------------------------------------------------------- launch ----
extern "C" void kernel_launch(void* const* d_in, const int* in_sizes, int n_in,
                              void* d_out, int out_size, void* d_ws, size_t ws_size,
                              hipStream_t stream) {
    const float* x    = (const float*)d_in[0];
    const float* qkvw = (const float*)d_in[1];
    const float* qkvb = (const float*)d_in[2];
    const float* outw = (const float*)d_in[3];
    const float* outb = (const float*)d_in[4];
    float* out = (float*)d_out;

    char* ws = (char*)d_ws;
    size_t off = 0;
    auto alloc = [&](size_t bytes) {
        void* p = ws + off;
        off += (bytes + 255) & ~(size_t)255;
        return p;
    };
    short* xb    = (short*)alloc((size_t)TOK * EMB * 2);
    short* wqkvT = (short*)alloc((size_t)QKV_N * EMB * 2);
    short* owT   = (short*)alloc((size_t)EMB * EMB * 2);
    short* q_ws  = (short*)alloc((size_t)NB * NH * S_LEN * HD * 2);
    short* k_ws  = (short*)alloc((size_t)NB * NH * S_LEN * HD * 2);
    short* v_ws  = (short*)alloc((size_t)NB * NH * S_LEN * HD * 2);
    short* vt_ws = (short*)alloc((size_t)NB * NH * S_LEN * HD * 2);
    short* attn  = (short*)alloc((size_t)TOK * EMB * 2);

    cvt_f32_bf16<<<(TOK * EMB / 4 + 255) / 256, 256, 0, stream>>>(x, xb, TOK * EMB);
    transpose_cvt<<<dim3(QKV_N / 32, EMB / 32), 256, 0, stream>>>(qkvw, wqkvT, EMB, QKV_N);
    transpose_cvt<<<dim3(EMB / 32, EMB / 32), 256, 0, stream>>>(outw, owT, EMB, EMB);

    gemm_bf16<0><<<dim3(QKV_N / 128, TOK / 128), 256, 0, stream>>>(
        xb, wqkvT, qkvb, q_ws, k_ws, v_ws, nullptr, TOK, QKV_N, EMB);

    vtrans<<<dim3(S_LEN / 32, HD / 32, NB * NH), 256, 0, stream>>>(v_ws, vt_ws);

    attn_fwd<<<1024, 256, 0, stream>>>(q_ws, k_ws, vt_ws, attn);

    gemm_bf16<1><<<dim3(EMB / 128, TOK / 128), 256, 0, stream>>>(
        attn, owT, outb, nullptr, nullptr, nullptr, out, TOK, EMB, EMB);
}

// Round 9
// 225.499 us; speedup vs baseline: 1.0802x; 1.0206x over previous
//
#include <hip/hip_runtime.h>
#include <stdint.h>

typedef short short4v __attribute__((ext_vector_type(4)));
typedef short short8  __attribute__((ext_vector_type(8)));
typedef float f32x4   __attribute__((ext_vector_type(4)));
typedef unsigned int u32x2 __attribute__((ext_vector_type(2)));

#define S_LEN 2048
#define NB    2
#define NH    16
#define HD    64
#define EMB   1024
#define TOK   (NB * S_LEN)     // 4096
#define QKV_N (3 * EMB)        // 3072

// async global->LDS, 16B per lane, LDS dest = wave-uniform base + lane*16
#define GLD16(gp, lp) __builtin_amdgcn_global_load_lds( \
    (const __attribute__((address_space(1))) void*)(gp), \
    (__attribute__((address_space(3))) void*)(lp), 16, 0, 0)

static __device__ __forceinline__ short f2bf(float f) {
    unsigned int x = __float_as_uint(f);
    unsigned int r = (x + 0x7fffu + ((x >> 16) & 1u)) >> 16;   // RNE
    return (short)(r & 0xffffu);
}

static __device__ __forceinline__ f32x4 mfma16(short8 a, short8 b, f32x4 c) {
    return __builtin_amdgcn_mfma_f32_16x16x32_bf16(a, b, c, 0, 0, 0);
}

// ---------------------------------------------------------------- prep ----
// One kernel, three block ranges:
//   [0,4096)      : x fp32 -> xb bf16 (4 elems/thread)
//   [4096,7168)   : qkv_w [1024][3072] -> wqkvT [3072][1024] bf16
//   [7168,8192)   : out_w [1024][1024] -> owT  [1024][1024] bf16
__global__ __launch_bounds__(256) void prep_fused(
    const float* __restrict__ x, const float* __restrict__ qkvw,
    const float* __restrict__ outw,
    short* __restrict__ xb, short* __restrict__ wqkvT, short* __restrict__ owT) {
    __shared__ float tile[32][33];
    const int blk = blockIdx.x;
    if (blk < 4096) {
        int i = (blk * 256 + threadIdx.x) * 4;
        float4 v = *reinterpret_cast<const float4*>(x + i);
        short4v o;
        o.x = f2bf(v.x); o.y = f2bf(v.y); o.z = f2bf(v.z); o.w = f2bf(v.w);
        *reinterpret_cast<short4v*>(xb + i) = o;
        return;
    }
    const float* w; short* wt; int K, N, bx, by;
    if (blk < 7168) {
        w = qkvw; wt = wqkvT; K = EMB; N = QKV_N;
        bx = (blk - 4096) % 96; by = (blk - 4096) / 96;
    } else {
        w = outw; wt = owT; K = EMB; N = EMB;
        bx = (blk - 7168) % 32; by = (blk - 7168) / 32;
    }
    int tx = threadIdx.x & 31, ty = threadIdx.x >> 5;   // 32 x 8
    int c0 = bx * 32, r0 = by * 32;
    #pragma unroll
    for (int j = 0; j < 4; j++)
        tile[ty + j * 8][tx] = w[(long)(r0 + ty + j * 8) * N + c0 + tx];
    __syncthreads();
    #pragma unroll
    for (int j = 0; j < 4; j++)
        wt[(long)(c0 + ty + j * 8) * K + r0 + tx] = f2bf(tile[tx][ty + j * 8]);
}

// ---------------------------------------------------------------- GEMM ----
// C[M][N] = A[M][K] @ BT[N][K]^T + bias.  BK=64, global_load_lds + XOR swizzle.
// EPI=0: Q,K -> [bh][s][d] bf16;  V -> Vt [bh][d][s] bf16 (direct transpose).
// EPI=1: fp32 row-major out.
template <int EPI>
__global__ __launch_bounds__(256) void gemm_bf16(
    const short* __restrict__ A, const short* __restrict__ BT,
    const float* __restrict__ bias,
    short* __restrict__ q_ws, short* __restrict__ k_ws, short* __restrict__ vt_ws,
    float* __restrict__ outf, int M, int N, int K) {
    __shared__ __align__(16) short As[128 * 64];
    __shared__ __align__(16) short Bs[128 * 64];
    const int tid = threadIdx.x;
    const int lane = tid & 63, wave = tid >> 6;
    const int wm = wave >> 1, wn = wave & 1;
    const int l15 = lane & 15, lhi = lane >> 4;
    const int bm = blockIdx.y, bn = blockIdx.x;

    const short* gA[4]; const short* gB[4]; short* lA[4]; short* lB[4];
    #pragma unroll
    for (int i = 0; i < 4; i++) {
        int inst = wave * 4 + i;                 // 0..15
        int row  = inst * 8 + (lane >> 3);       // 0..127
        int c    = lane & 7, cp = c ^ (row & 7); // 16B-granule swizzle
        gA[i] = A  + (long)(bm * 128 + row) * K + cp * 8;
        gB[i] = BT + (long)(bn * 128 + row) * K + cp * 8;
        lA[i] = As + inst * 512;
        lB[i] = Bs + inst * 512;
    }

    f32x4 acc[4][4] = {};
    for (int kt = 0; kt < K; kt += 64) {
        #pragma unroll
        for (int i = 0; i < 4; i++) { GLD16(gA[i] + kt, lA[i]); GLD16(gB[i] + kt, lB[i]); }
        __syncthreads();
        #pragma unroll
        for (int ks = 0; ks < 2; ks++) {
            short8 af[4], bfr[4];
            #pragma unroll
            for (int m = 0; m < 4; m++) {
                int row = wm * 64 + m * 16 + l15;
                int cp  = (ks * 4 + lhi) ^ (row & 7);
                af[m] = *(const short8*)(As + row * 64 + cp * 8);
            }
            #pragma unroll
            for (int n = 0; n < 4; n++) {
                int row = wn * 64 + n * 16 + l15;
                int cp  = (ks * 4 + lhi) ^ (row & 7);
                bfr[n] = *(const short8*)(Bs + row * 64 + cp * 8);
            }
            #pragma unroll
            for (int m = 0; m < 4; m++)
                #pragma unroll
                for (int n = 0; n < 4; n++)
                    acc[m][n] = mfma16(af[m], bfr[n], acc[m][n]);
        }
        __syncthreads();
    }

    if (EPI == 0) {
        const int part = bn >> 3;                // 1024-aligned: uniform per block
        if (part < 2) {
            short* dst = part == 0 ? q_ws : k_ws;
            #pragma unroll
            for (int m = 0; m < 4; m++) {
                const int row0 = bm * 128 + wm * 64 + m * 16 + lhi * 4;
                #pragma unroll
                for (int n = 0; n < 4; n++) {
                    const int col = bn * 128 + wn * 64 + n * 16 + l15;
                    const float bv = bias[col];
                    const int nn = col & 1023, h = nn >> 6, d = nn & 63;
                    #pragma unroll
                    for (int r = 0; r < 4; r++) {
                        const int rr = row0 + r, b = rr >> 11, s = rr & 2047;
                        dst[((long)(b * NH + h) * S_LEN + s) * HD + d] =
                            f2bf(acc[m][n][r] + bv);
                    }
                }
            }
        } else {
            // V: write transposed [bh][d][s]; 4 consecutive s per lane -> 8B store
            #pragma unroll
            for (int m = 0; m < 4; m++) {
                const int row0 = bm * 128 + wm * 64 + m * 16 + lhi * 4;
                const int b = row0 >> 11, s0 = row0 & 2047;
                #pragma unroll
                for (int n = 0; n < 4; n++) {
                    const int col = bn * 128 + wn * 64 + n * 16 + l15;
                    const float bv = bias[col];
                    const int nn = col & 1023, h = nn >> 6, d = nn & 63;
                    unsigned w0 = (unsigned)(unsigned short)f2bf(acc[m][n][0] + bv) |
                                  ((unsigned)(unsigned short)f2bf(acc[m][n][1] + bv) << 16);
                    unsigned w1 = (unsigned)(unsigned short)f2bf(acc[m][n][2] + bv) |
                                  ((unsigned)(unsigned short)f2bf(acc[m][n][3] + bv) << 16);
                    u32x2 w; w[0] = w0; w[1] = w1;
                    *(u32x2*)&vt_ws[((long)(b * NH + h) * HD + d) * S_LEN + s0] = w;
                }
            }
        }
    } else {
        #pragma unroll
        for (int m = 0; m < 4; m++) {
            const int row0 = bm * 128 + wm * 64 + m * 16 + lhi * 4;
            #pragma unroll
            for (int n = 0; n < 4; n++) {
                const int col = bn * 128 + wn * 64 + n * 16 + l15;
                const float bv = bias[col];
                #pragma unroll
                for (int r = 0; r < 4; r++)
                    outf[(long)(row0 + r) * N + col] = acc[m][n][r] + bv;
            }
        }
    }
}

// ----------------------------------------------------------- attention ----
// Q,K: [bh][s][d].  Vt: [bh][d][s].  O: [b][s][e] bf16.
// 4 waves x 16 q-rows; KVBLK=64.  K double-buffered, V single-buffered;
// 2 barriers/tile.  LDS 33792 B.  Round-2-proven softmax numerics.
// T5: setprio(1) around MFMA clusters.
__global__ __launch_bounds__(256) void attn_fwd(const short* __restrict__ Qg,
                                                const short* __restrict__ Kg,
                                                const short* __restrict__ Vtg,
                                                short* __restrict__ Og) {
    __shared__ __align__(16) short Ks[2][4096];
    __shared__ __align__(16) short Vs[4096];
    __shared__ __align__(16) short Pl[4][16][72];
    const int tid = threadIdx.x, lane = tid & 63, wave = tid >> 6;
    const int l15 = lane & 15, lhi = lane >> 4;
    // bijective XCD swizzle: 1024 wgs, 8 XCDs -> 4 heads per XCD's L2
    const int wg  = blockIdx.x;
    const int swz = (wg & 7) * 128 + (wg >> 3);
    const int bh  = swz >> 5;
    const int qt  = swz & 31;
    const int q0 = qt * 64 + wave * 16;
    const long kbase = (long)bh * S_LEN * HD;
    const long vbase = (long)bh * HD * S_LEN;

    short8 qf[2];
    #pragma unroll
    for (int ks2 = 0; ks2 < 2; ks2++)
        qf[ks2] = *(const short8*)&Qg[kbase + (long)(q0 + l15) * HD + ks2 * 32 + lhi * 8];

    const short* gKp[2]; const short* gVp[2]; int lOff[2];
    #pragma unroll
    for (int i = 0; i < 2; i++) {
        int inst = wave * 2 + i;                 // 0..7
        int row  = inst * 8 + (lane >> 3);       // 0..63
        int cp   = (lane & 7) ^ (row & 7);
        gKp[i] = Kg  + kbase + (long)row * HD + cp * 8;
        gVp[i] = Vtg + vbase + (long)row * S_LEN + cp * 8;
        lOff[i] = inst * 512;
    }

    // loop-invariant swizzled fragment offsets (element units)
    int fOff[4][2];
    #pragma unroll
    for (int sub = 0; sub < 4; sub++)
        #pragma unroll
        for (int ks2 = 0; ks2 < 2; ks2++) {
            int row = sub * 16 + l15;
            int cp  = (ks2 * 4 + lhi) ^ (l15 & 7);
            fOff[sub][ks2] = row * 64 + cp * 8;
        }

    f32x4 accO[4] = {};
    float ms = -1e30f, lp = 0.f;
    const float C2 = 0.18033688f;   // (1/sqrt(64)) * log2(e)

    // prologue: stage K(0) only; V(0) staged at t=0 tile top
    #pragma unroll
    for (int i = 0; i < 2; i++) GLD16(gKp[i], &Ks[0][lOff[i]]);
    __syncthreads();

    const int NT = S_LEN / 64;
    for (int t = 0; t < NT; t++) {
        const int cur = t & 1;
        // stage V(t) into single buffer (safe: barrier-B of t-1 passed);
        // consumed after barrier-A below.
        #pragma unroll
        for (int i = 0; i < 2; i++) GLD16(gVp[i] + t * 64, &Vs[lOff[i]]);
        // stage K(t+1) into the other K half
        if (t + 1 < NT) {
            #pragma unroll
            for (int i = 0; i < 2; i++)
                GLD16(gKp[i] + (long)(t + 1) * 4096, &Ks[cur ^ 1][lOff[i]]);
        }

        // S = Q K^T -> lane holds S[q=l15][k=sub*16+lhi*4+r]
        f32x4 accS[4];
        __builtin_amdgcn_s_setprio(1);
        #pragma unroll
        for (int sub = 0; sub < 4; sub++) {
            f32x4 z = {0.f, 0.f, 0.f, 0.f};
            #pragma unroll
            for (int ks2 = 0; ks2 < 2; ks2++) {
                short8 kf = *(const short8*)&Ks[cur][fOff[sub][ks2]];
                z = mfma16(kf, qf[ks2], z);
            }
            accS[sub] = z;
        }
        __builtin_amdgcn_s_setprio(0);

        // row max: in-register tree + 2 cross-lhi shuffles
        f32x4 mx = accS[0];
        #pragma unroll
        for (int sub = 1; sub < 4; sub++)
            #pragma unroll
            for (int r = 0; r < 4; r++) mx[r] = fmaxf(mx[r], accS[sub][r]);
        float m4 = fmaxf(fmaxf(mx[0], mx[1]), fmaxf(mx[2], mx[3]));
        m4 = fmaxf(m4, __shfl_xor(m4, 16));
        m4 = fmaxf(m4, __shfl_xor(m4, 32));
        float msc = m4 * C2;

        // defer-max (T13): rescale only when max grew by > 8 (exp2 domain)
        if (__any(msc > ms + 8.f)) {
            float msn = fmaxf(ms, msc);
            float corr = exp2f(ms - msn);
            ms = msn;
            lp *= corr;
            #pragma unroll
            for (int r = 0; r < 4; r++) {
                float cr = __shfl(corr, lhi * 4 + r);   // corr of q-row (lhi*4+r)
                #pragma unroll
                for (int ds = 0; ds < 4; ds++) accO[ds][r] *= cr;
            }
        }

        // P = exp2(S*C2 - ms); per-lane f32 partial sum; pack bf16, b64 write
        float lsum = 0.f;
        #pragma unroll
        for (int sub = 0; sub < 4; sub++) {
            f32x4 p;
            #pragma unroll
            for (int r = 0; r < 4; r++)
                p[r] = exp2f(fmaf(accS[sub][r], C2, -ms));
            lsum += (p[0] + p[1]) + (p[2] + p[3]);
            unsigned pa, pb;
            asm("v_cvt_pk_bf16_f32 %0, %1, %2" : "=v"(pa) : "v"(p[0]), "v"(p[1]));
            asm("v_cvt_pk_bf16_f32 %0, %1, %2" : "=v"(pb) : "v"(p[2]), "v"(p[3]));
            u32x2 w; w[0] = pa; w[1] = pb;
            *(u32x2*)(&Pl[wave][l15][sub * 16 + lhi * 4]) = w;
        }
        lp += lsum;

        // barrier-A: drains vmcnt (V(t), K(t+1) landed) and lgkm (Pl visible)
        __syncthreads();

        short8 pf0 = *(const short8*)(&Pl[wave][l15][lhi * 8]);
        short8 pf1 = *(const short8*)(&Pl[wave][l15][32 + lhi * 8]);
        // O += P V
        __builtin_amdgcn_s_setprio(1);
        #pragma unroll
        for (int ds = 0; ds < 4; ds++) {
            short8 vf0 = *(const short8*)&Vs[fOff[ds][0]];
            short8 vf1 = *(const short8*)&Vs[fOff[ds][1]];
            accO[ds] = mfma16(pf0, vf0, accO[ds]);
            accO[ds] = mfma16(pf1, vf1, accO[ds]);
        }
        __builtin_amdgcn_s_setprio(0);
        // barrier-B: protect Vs (and Pl) before next tile overwrites
        __syncthreads();
    }

    // final: reduce row sums across lhi, redistribute to accO layout, store
    float L = lp + __shfl_xor(lp, 16);
    L += __shfl_xor(L, 32);
    const int b = bh >> 4, h = bh & 15;
    #pragma unroll
    for (int r = 0; r < 4; r++) {
        float Lr  = __shfl(L, lhi * 4 + r);
        float inv = 1.f / Lr;
        const int s = q0 + lhi * 4 + r;
        #pragma unroll
        for (int ds = 0; ds < 4; ds++)
            Og[((long)(b * S_LEN + s)) * EMB + h * 64 + ds * 16 + l15] =
                f2bf(accO[ds][r] * inv);
    }
}

// -------------------------------------------------------------- launch ----
extern "C" void kernel_launch(void* const* d_in, const int* in_sizes, int n_in,
                              void* d_out, int out_size, void* d_ws, size_t ws_size,
                              hipStream_t stream) {
    const float* x    = (const float*)d_in[0];
    const float* qkvw = (const float*)d_in[1];
    const float* qkvb = (const float*)d_in[2];
    const float* outw = (const float*)d_in[3];
    const float* outb = (const float*)d_in[4];
    float* out = (float*)d_out;

    char* ws = (char*)d_ws;
    size_t off = 0;
    auto alloc = [&](size_t bytes) {
        void* p = ws + off;
        off += (bytes + 255) & ~(size_t)255;
        return p;
    };
    short* xb    = (short*)alloc((size_t)TOK * EMB * 2);
    short* wqkvT = (short*)alloc((size_t)QKV_N * EMB * 2);
    short* owT   = (short*)alloc((size_t)EMB * EMB * 2);
    short* q_ws  = (short*)alloc((size_t)NB * NH * S_LEN * HD * 2);
    short* k_ws  = (short*)alloc((size_t)NB * NH * S_LEN * HD * 2);
    short* vt_ws = (short*)alloc((size_t)NB * NH * S_LEN * HD * 2);
    short* attn  = (short*)alloc((size_t)TOK * EMB * 2);

    prep_fused<<<8192, 256, 0, stream>>>(x, qkvw, outw, xb, wqkvT, owT);

    gemm_bf16<0><<<dim3(QKV_N / 128, TOK / 128), 256, 0, stream>>>(
        xb, wqkvT, qkvb, q_ws, k_ws, vt_ws, nullptr, TOK, QKV_N, EMB);

    attn_fwd<<<1024, 256, 0, stream>>>(q_ws, k_ws, vt_ws, attn);

    gemm_bf16<1><<<dim3(EMB / 128, TOK / 128), 256, 0, stream>>>(
        attn, owT, outb, nullptr, nullptr, nullptr, out, TOK, EMB, EMB);
}